// Round 1
// baseline (226.323 us; speedup 1.0000x reference)
//
#include <hip/hip_runtime.h>
#include <hip/hip_bf16.h>
#include <stdint.h>
#include <stddef.h>

// ---------- types ----------
typedef __attribute__((ext_vector_type(8))) short bf16x8;   // 8 bf16 (4 VGPR)
typedef __attribute__((ext_vector_type(4))) short bf16x4;   // 4 bf16 (2 VGPR)
typedef __attribute__((ext_vector_type(4))) float f32x4;
typedef __attribute__((ext_vector_type(4))) unsigned short u16x4;

#define DEVI static __device__ __forceinline__

// problem constants
static constexpr int BATCH = 4;
static constexpr int SEQ   = 2048;
static constexpr int HEADS = 16;
static constexpr int DHEAD = 64;
static constexpr int DMODEL = 1024;
static constexpr int MROWS = BATCH * SEQ;          // 8192
static constexpr int NQKV  = 3 * DMODEL;           // 3072

DEVI unsigned short f2bf(float f) {
  union { float f; unsigned int u; } c; c.f = f;
  unsigned int u = c.u;
  unsigned int r = u + 0x7fffu + ((u >> 16) & 1u);   // RNE
  return (unsigned short)(r >> 16);
}

DEVI void gload_lds16(const void* g, void* l) {
  __builtin_amdgcn_global_load_lds(
      (const __attribute__((address_space(1))) void*)g,
      (__attribute__((address_space(3))) void*)l, 16, 0, 0);
}

// ---------- fp32 -> bf16 convert (vectorized, n multiple of 4) ----------
__global__ void cvt_f32_bf16(const float* __restrict__ src,
                             unsigned short* __restrict__ dst, int n4) {
  int i = blockIdx.x * blockDim.x + threadIdx.x;
  if (i >= n4) return;
  f32x4 v = *(const f32x4*)(src + (size_t)i * 4);
  u16x4 o;
  o[0] = f2bf(v[0]); o[1] = f2bf(v[1]); o[2] = f2bf(v[2]); o[3] = f2bf(v[3]);
  *(u16x4*)(dst + (size_t)i * 4) = o;
}

// ---------- WO[h][d][v] (fp32) -> WOt[d][h*64+v] (bf16) ----------
__global__ void wot_kernel(const float* __restrict__ WO,
                           unsigned short* __restrict__ WOt) {
  int i = blockIdx.x * 256 + threadIdx.x;      // 1M threads
  int d = i >> 10, k = i & 1023;
  int h = k >> 6, v = k & 63;
  WOt[i] = f2bf(WO[(size_t)(h * 1024 + d) * 64 + v]);
}

// ---------- bf16 GEMM: C[M,N] = A[M,K] * Bt[N,K]^T ----------
// 128x128 tile, BK=64, 4 waves, global_load_lds w/ pre-swizzled source,
// XOR-swizzled LDS reads (conflict ~2-way).
template <bool OUTBF>
__global__ __launch_bounds__(256)
void gemm_bt(const unsigned short* __restrict__ A,
             const unsigned short* __restrict__ Bt,
             void* __restrict__ Cv, int M, int N, int K, int ldc) {
  __shared__ unsigned short As[128 * 64];
  __shared__ unsigned short Bs[128 * 64];
  const int tid = threadIdx.x;
  const int lane = tid & 63;
  const int w = tid >> 6;
  const int wr = w >> 1, wc = w & 1;
  const int l15 = lane & 15, l4 = lane >> 4;
  const int nbn = N >> 7;
  const int mblk = blockIdx.x / nbn, nblk = blockIdx.x % nbn;
  const unsigned short* Ab = A + (size_t)mblk * 128 * K;
  const unsigned short* Bb = Bt + (size_t)nblk * 128 * K;
  f32x4 acc[4][4] = {};

  const int srow = tid >> 3;     // staging: chunk c = tid + i*256 -> row=c>>3, pos=c&7
  const int spos = tid & 7;

  for (int k0 = 0; k0 < K; k0 += 64) {
#pragma unroll
    for (int i = 0; i < 4; ++i) {
      int row = srow + i * 32;
      int sc = spos ^ (row & 7);   // pre-swizzled source so linear LDS write = swizzled layout
      gload_lds16(Ab + (size_t)row * K + k0 + sc * 8, (void*)(As + (tid + i * 256) * 8));
      gload_lds16(Bb + (size_t)row * K + k0 + sc * 8, (void*)(Bs + (tid + i * 256) * 8));
    }
    __syncthreads();
    bf16x8 af[2][4], bq[2][4];
#pragma unroll
    for (int cc = 0; cc < 2; ++cc) {
#pragma unroll
      for (int m = 0; m < 4; ++m) {
        int ra = wr * 64 + m * 16 + l15;
        af[cc][m] = *(const bf16x8*)(As + ra * 64 + (((cc * 4 + l4) ^ (ra & 7)) * 8));
        int rb = wc * 64 + m * 16 + l15;
        bq[cc][m] = *(const bf16x8*)(Bs + rb * 64 + (((cc * 4 + l4) ^ (rb & 7)) * 8));
      }
    }
#pragma unroll
    for (int cc = 0; cc < 2; ++cc)
#pragma unroll
      for (int m = 0; m < 4; ++m)
#pragma unroll
        for (int n = 0; n < 4; ++n)
          acc[m][n] = __builtin_amdgcn_mfma_f32_16x16x32_bf16(af[cc][m], bq[cc][n], acc[m][n], 0, 0, 0);
    __syncthreads();
  }

#pragma unroll
  for (int m = 0; m < 4; ++m)
#pragma unroll
    for (int n = 0; n < 4; ++n) {
      int col = nblk * 128 + wc * 64 + n * 16 + l15;
#pragma unroll
      for (int j = 0; j < 4; ++j) {
        int row = mblk * 128 + wr * 64 + m * 16 + l4 * 4 + j;   // D: col=l&15, row=(l>>4)*4+j
        if (OUTBF)
          ((unsigned short*)Cv)[(size_t)row * ldc + col] = f2bf(acc[m][n][j]);
        else
          ((float*)Cv)[(size_t)row * ldc + col] = acc[m][n][j];
      }
    }
}

// ---------- flash attention (causal) ----------
// QKV: [8192][3072] bf16 rows = (b*S+s), cols: Q=h*64+k, K=1024+h*64+k, V=2048+h*64+v
// Out: [8192][1024] bf16 rows = (b*S+s), col h*64+v
// block = 4 waves; wave owns 16 q-rows; kv-tile = 32.
// Swapped QK^T: T = K_tile * Q^T  (T[kv][q]) so P^T register layout feeds PV A-operand.
__global__ __launch_bounds__(256)
void attn_fwd(const unsigned short* __restrict__ QKV,
              unsigned short* __restrict__ Oout) {
  __shared__ unsigned short Ks[32 * 64];   // swizzled rows
  __shared__ unsigned short Vt[64 * 36];   // V^T, padded stride 36 (conflict-free b64 reads)
  const int bid = blockIdx.x;
  const int qi = 31 - (bid >> 6);          // reversed: big blocks dispatch first
  const int bh = bid & 63;
  const int b = bh >> 4, h = bh & 15;
  const int tid = threadIdx.x, lane = tid & 63, w = tid >> 6;
  const int l15 = lane & 15, l4 = lane >> 4;
  const int qbase = qi * 64 + w * 16;

  // Q fragments (B-operand: lane holds Q[q=l15][d=(l>>4)*8+j], d-halves 0/1)
  const size_t qrow = (size_t)(b * SEQ + qbase + l15) * NQKV + h * 64;
  bf16x8 Qf0 = *(const bf16x8*)(QKV + qrow + l4 * 8);
  bf16x8 Qf1 = *(const bf16x8*)(QKV + qrow + 32 + l4 * 8);

  const unsigned short* Kbase = QKV + (size_t)b * SEQ * NQKV + 1024 + h * 64;
  const unsigned short* Vbase = QKV + (size_t)b * SEQ * NQKV + 2048 + h * 64;

  f32x4 O[4] = {};
  float mrun = -1e30f, lrun = 0.f;
  const int nt = 2 * qi + 2;                       // tiles for last wave
  const int mytiles = ((qbase + 15) >> 5) + 1;     // tiles this wave computes
  const float c1s = 0.1803368801111204f;           // (1/sqrt(64)) * log2(e)

  const int skrow = tid >> 3, skpos = tid & 7;
  const int ksc = skpos ^ (skrow & 7);
  const int vkv = tid >> 3, vv0 = (tid & 7) * 8;

  for (int t = 0; t < nt; ++t) {
    const int kv0 = t * 32;
    // stage K tile (32 rows x 64d), swizzled source -> linear LDS
    gload_lds16(Kbase + (size_t)(kv0 + skrow) * NQKV + ksc * 8, (void*)(Ks + tid * 8));
    // stage V^T (64v x 32kv, pad 36)
    {
      bf16x8 vv = *(const bf16x8*)(Vbase + (size_t)(kv0 + vkv) * NQKV + vv0);
#pragma unroll
      for (int j = 0; j < 8; ++j) Vt[(vv0 + j) * 36 + vkv] = (unsigned short)vv[j];
    }
    __syncthreads();
    if (t < mytiles) {
      f32x4 T0 = {}, T1 = {};
      {
        const int r0 = l15, r1 = 16 + l15;
        bf16x8 k00 = *(const bf16x8*)(Ks + r0 * 64 + ((l4 ^ (r0 & 7)) * 8));
        bf16x8 k01 = *(const bf16x8*)(Ks + r0 * 64 + (((4 + l4) ^ (r0 & 7)) * 8));
        bf16x8 k10 = *(const bf16x8*)(Ks + r1 * 64 + ((l4 ^ (r1 & 7)) * 8));
        bf16x8 k11 = *(const bf16x8*)(Ks + r1 * 64 + (((4 + l4) ^ (r1 & 7)) * 8));
        T0 = __builtin_amdgcn_mfma_f32_16x16x32_bf16(k00, Qf0, T0, 0, 0, 0);
        T0 = __builtin_amdgcn_mfma_f32_16x16x32_bf16(k01, Qf1, T0, 0, 0, 0);
        T1 = __builtin_amdgcn_mfma_f32_16x16x32_bf16(k10, Qf0, T1, 0, 0, 0);
        T1 = __builtin_amdgcn_mfma_f32_16x16x32_bf16(k11, Qf1, T1, 0, 0, 0);
      }
      // causal mask: only the wave's diagonal tile can violate kv<=q
      if (t == mytiles - 1) {
        const int qg = qbase + l15;
#pragma unroll
        for (int r = 0; r < 4; ++r) {
          if (kv0 + l4 * 4 + r > qg) T0[r] = -1e30f;
          if (kv0 + 16 + l4 * 4 + r > qg) T1[r] = -1e30f;
        }
      }
      // online softmax (stats per q = l15, replicated across l4 groups)
      float mx = fmaxf(fmaxf(fmaxf(T0[0], T0[1]), fmaxf(T0[2], T0[3])),
                       fmaxf(fmaxf(T1[0], T1[1]), fmaxf(T1[2], T1[3])));
      mx = fmaxf(mx, __shfl_xor(mx, 16));
      mx = fmaxf(mx, __shfl_xor(mx, 32));
      mx *= c1s;
      const float mnew = fmaxf(mrun, mx);
      float p[8];
#pragma unroll
      for (int r = 0; r < 4; ++r) p[r] = exp2f(T0[r] * c1s - mnew);
#pragma unroll
      for (int r = 0; r < 4; ++r) p[4 + r] = exp2f(T1[r] * c1s - mnew);
      float rs = 0.f;
#pragma unroll
      for (int r = 0; r < 8; ++r) rs += p[r];
      rs += __shfl_xor(rs, 16);
      rs += __shfl_xor(rs, 32);
      const float alpha = exp2f(mrun - mnew);
      lrun = lrun * alpha + rs;
      mrun = mnew;
      // O rows are q=4*l4+j -> fetch alpha from lane q
      float a0 = __shfl(alpha, l4 * 4 + 0);
      float a1 = __shfl(alpha, l4 * 4 + 1);
      float a2 = __shfl(alpha, l4 * 4 + 2);
      float a3 = __shfl(alpha, l4 * 4 + 3);
#pragma unroll
      for (int vb = 0; vb < 4; ++vb) {
        O[vb][0] *= a0; O[vb][1] *= a1; O[vb][2] *= a2; O[vb][3] *= a3;
      }
      // P^T regs already match 16x16x16 A-operand layout (q=l15, kv=4*l4+r)
      bf16x4 pb0, pb1;
#pragma unroll
      for (int r = 0; r < 4; ++r) {
        pb0[r] = (short)f2bf(p[r]);
        pb1[r] = (short)f2bf(p[4 + r]);
      }
#pragma unroll
      for (int vb = 0; vb < 4; ++vb) {
        const int v = vb * 16 + l15;
        bf16x4 vf0 = *(const bf16x4*)(Vt + v * 36 + l4 * 4);
        bf16x4 vf1 = *(const bf16x4*)(Vt + v * 36 + 16 + l4 * 4);
        O[vb] = __builtin_amdgcn_mfma_f32_16x16x16bf16_1k(pb0, vf0, O[vb], 0, 0, 0);
        O[vb] = __builtin_amdgcn_mfma_f32_16x16x16bf16_1k(pb1, vf1, O[vb], 0, 0, 0);
      }
    }
    __syncthreads();
  }
  const float linv = 1.f / lrun;
  float i0 = __shfl(linv, l4 * 4 + 0);
  float i1 = __shfl(linv, l4 * 4 + 1);
  float i2 = __shfl(linv, l4 * 4 + 2);
  float i3 = __shfl(linv, l4 * 4 + 3);
#pragma unroll
  for (int vb = 0; vb < 4; ++vb) {
    const size_t base = (size_t)(b * SEQ + qbase) * 1024 + h * 64 + vb * 16 + l15;
    Oout[base + (size_t)(l4 * 4 + 0) * 1024] = f2bf(O[vb][0] * i0);
    Oout[base + (size_t)(l4 * 4 + 1) * 1024] = f2bf(O[vb][1] * i1);
    Oout[base + (size_t)(l4 * 4 + 2) * 1024] = f2bf(O[vb][2] * i2);
    Oout[base + (size_t)(l4 * 4 + 3) * 1024] = f2bf(O[vb][3] * i3);
  }
}

// ---------- launcher ----------
extern "C" void kernel_launch(void* const* d_in, const int* in_sizes, int n_in,
                              void* d_out, int out_size, void* d_ws, size_t ws_size,
                              hipStream_t stream) {
  const float* x  = (const float*)d_in[0];
  const float* WQ = (const float*)d_in[1];
  const float* WK = (const float*)d_in[2];
  const float* WV = (const float*)d_in[3];
  const float* WO = (const float*)d_in[4];
  float* out = (float*)d_out;

  char* ws = (char*)d_ws;
  // ws layout (bytes):
  //   QKVb : 8192*3072*2 = 50331648
  //   xb   : 8192*1024*2 = 16777216   (reused as attn output after QKV GEMM)
  //   Wqkv : 3072*1024*2 =  6291456
  //   WOt  : 1024*1024*2 =  2097152   -> total 75.5 MB
  unsigned short* QKVb  = (unsigned short*)ws;
  unsigned short* xb    = (unsigned short*)(ws + 50331648);
  unsigned short* Wqkv  = (unsigned short*)(ws + 67108864);
  unsigned short* WOt   = (unsigned short*)(ws + 73400320);
  unsigned short* attnb = xb;   // safe reuse: xb consumed by QKV GEMM before attn writes

  // converts
  cvt_f32_bf16<<<8192, 256, 0, stream>>>(x, xb, 2097152);               // 8.4M elems
  cvt_f32_bf16<<<1024, 256, 0, stream>>>(WQ, Wqkv, 262144);             // 1M elems
  cvt_f32_bf16<<<1024, 256, 0, stream>>>(WK, Wqkv + 1048576, 262144);
  cvt_f32_bf16<<<1024, 256, 0, stream>>>(WV, Wqkv + 2097152, 262144);
  wot_kernel<<<4096, 256, 0, stream>>>(WO, WOt);

  // fused QKV projection: [8192,1024] x [3072,1024]^T -> [8192,3072] bf16
  gemm_bt<true><<<(MROWS / 128) * (NQKV / 128), 256, 0, stream>>>(
      xb, Wqkv, QKVb, MROWS, NQKV, DMODEL, NQKV);

  // causal flash attention -> attnb [8192,1024] bf16
  attn_fwd<<<(SEQ / 64) * (BATCH * HEADS), 256, 0, stream>>>(QKVb, attnb);

  // output projection: [8192,1024] x [1024,1024]^T -> [8192,1024] fp32
  gemm_bt<false><<<(MROWS / 128) * (DMODEL / 128), 256, 0, stream>>>(
      attnb, WOt, out, MROWS, DMODEL, DMODEL, DMODEL);
}

// Round 3
// 210.803 us; speedup vs baseline: 1.0736x; 1.0736x over previous
//
#include <hip/hip_runtime.h>
#include <hip/hip_bf16.h>
#include <stdint.h>
#include <stddef.h>

// ---------- types ----------
typedef __attribute__((ext_vector_type(8))) short bf16x8;   // 8 bf16 (4 VGPR)
typedef __attribute__((ext_vector_type(4))) short bf16x4;   // 4 bf16 (2 VGPR)
typedef __attribute__((ext_vector_type(4))) float f32x4;
typedef __attribute__((ext_vector_type(4))) unsigned short u16x4;

#define DEVI static __device__ __forceinline__

// problem constants
static constexpr int BATCH = 4;
static constexpr int SEQ   = 2048;
static constexpr int DMODEL = 1024;
static constexpr int MROWS = BATCH * SEQ;          // 8192

DEVI unsigned short f2bf(float f) {
  union { float f; unsigned int u; } c; c.f = f;
  unsigned int u = c.u;
  unsigned int r = u + 0x7fffu + ((u >> 16) & 1u);   // RNE
  return (unsigned short)(r >> 16);
}

DEVI void gload_lds16(const void* g, void* l) {
  __builtin_amdgcn_global_load_lds(
      (const __attribute__((address_space(1))) void*)g,
      (__attribute__((address_space(3))) void*)l, 16, 0, 0);
}

// ---------- fp32 -> bf16 convert (vectorized, n multiple of 4) ----------
__global__ void cvt_f32_bf16(const float* __restrict__ src,
                             unsigned short* __restrict__ dst, int n4) {
  int i = blockIdx.x * blockDim.x + threadIdx.x;
  if (i >= n4) return;
  f32x4 v = *(const f32x4*)(src + (size_t)i * 4);
  u16x4 o;
  o[0] = f2bf(v[0]); o[1] = f2bf(v[1]); o[2] = f2bf(v[2]); o[3] = f2bf(v[3]);
  *(u16x4*)(dst + (size_t)i * 4) = o;
}

// ---------- WO[h][d][v] (fp32) -> WOt[d][h*64+v] (bf16) ----------
__global__ void wot_kernel(const float* __restrict__ WO,
                           unsigned short* __restrict__ WOt) {
  int i = blockIdx.x * 256 + threadIdx.x;      // 1M threads
  int d = i >> 10, k = i & 1023;
  int h = k >> 6, v = k & 63;
  WOt[i] = f2bf(WO[(size_t)(h * 1024 + d) * 64 + v]);
}

// ---------- bf16 GEMM: C[M,N] = A[M,K] * Bt[N,K]^T ----------
// 128x128 tile, BK=64, 4 waves, global_load_lds w/ pre-swizzled source,
// XOR-swizzled LDS reads (conflict ~2-way).  [round-1 verified]
template <bool OUTBF>
__global__ __launch_bounds__(256)
void gemm_bt(const unsigned short* __restrict__ A,
             const unsigned short* __restrict__ Bt,
             void* __restrict__ Cv, int M, int N, int K, int ldc) {
  __shared__ unsigned short As[128 * 64];
  __shared__ unsigned short Bs[128 * 64];
  const int tid = threadIdx.x;
  const int lane = tid & 63;
  const int w = tid >> 6;
  const int wr = w >> 1, wc = w & 1;
  const int l15 = lane & 15, l4 = lane >> 4;
  const int nbn = N >> 7;
  const int mblk = blockIdx.x / nbn, nblk = blockIdx.x % nbn;
  const unsigned short* Ab = A + (size_t)mblk * 128 * K;
  const unsigned short* Bb = Bt + (size_t)nblk * 128 * K;
  f32x4 acc[4][4] = {};

  const int srow = tid >> 3;     // staging: chunk c = tid + i*256 -> row=c>>3, pos=c&7
  const int spos = tid & 7;

  for (int k0 = 0; k0 < K; k0 += 64) {
#pragma unroll
    for (int i = 0; i < 4; ++i) {
      int row = srow + i * 32;
      int sc = spos ^ (row & 7);   // pre-swizzled source so linear LDS write = swizzled layout
      gload_lds16(Ab + (size_t)row * K + k0 + sc * 8, (void*)(As + (tid + i * 256) * 8));
      gload_lds16(Bb + (size_t)row * K + k0 + sc * 8, (void*)(Bs + (tid + i * 256) * 8));
    }
    __syncthreads();
    bf16x8 af[2][4], bq[2][4];
#pragma unroll
    for (int cc = 0; cc < 2; ++cc) {
#pragma unroll
      for (int m = 0; m < 4; ++m) {
        int ra = wr * 64 + m * 16 + l15;
        af[cc][m] = *(const bf16x8*)(As + ra * 64 + (((cc * 4 + l4) ^ (ra & 7)) * 8));
        int rb = wc * 64 + m * 16 + l15;
        bq[cc][m] = *(const bf16x8*)(Bs + rb * 64 + (((cc * 4 + l4) ^ (rb & 7)) * 8));
      }
    }
#pragma unroll
    for (int cc = 0; cc < 2; ++cc)
#pragma unroll
      for (int m = 0; m < 4; ++m)
#pragma unroll
        for (int n = 0; n < 4; ++n)
          acc[m][n] = __builtin_amdgcn_mfma_f32_16x16x32_bf16(af[cc][m], bq[cc][n], acc[m][n], 0, 0, 0);
    __syncthreads();
  }

#pragma unroll
  for (int m = 0; m < 4; ++m)
#pragma unroll
    for (int n = 0; n < 4; ++n) {
      int col = nblk * 128 + wc * 64 + n * 16 + l15;
#pragma unroll
      for (int j = 0; j < 4; ++j) {
        int row = mblk * 128 + wr * 64 + m * 16 + l4 * 4 + j;   // D: col=l&15, row=(l>>4)*4+j
        if (OUTBF)
          ((unsigned short*)Cv)[(size_t)row * ldc + col] = f2bf(acc[m][n][j]);
        else
          ((float*)Cv)[(size_t)row * ldc + col] = acc[m][n][j];
      }
    }
}

// ---------- flash attention (causal), v3 — conservative ----------
// QKb: [8192][2048] bf16, row (b*S+s): Q at col h*64+k, K at col 1024+h*64+k
// Vt : [1024][8192] bf16, row (h*64+v), col (b*S+s)  — V^T produced by GEMM
// Out: [8192][1024] bf16, row (b*S+s), col h*64+v
// Block = 4 waves; wave owns 16 q-rows; block covers 64 q; KV tile = 64.
// Single LDS buffer, 2 barriers/iter (round-1 structure).
// Swapped QK^T: T = K_tile * Q^T (T[kv][q]) so P^T register layout feeds PV A-operand.
// All 4 sub-tiles computed every tile; last tile masked with universal kv>q.
__global__ __launch_bounds__(256)
void attn_fwd(const unsigned short* __restrict__ QKb,
              const unsigned short* __restrict__ Vt,
              unsigned short* __restrict__ Oout) {
  __shared__ unsigned short Ks[64 * 64];
  __shared__ unsigned short Vs[64 * 64];
  const int bid = blockIdx.x;
  const int qi = 31 - (bid >> 6);          // reversed: heavy blocks dispatch first
  const int bh = bid & 63;
  const int b = bh >> 4, h = bh & 15;
  const int tid = threadIdx.x, lane = tid & 63, w = tid >> 6;
  const int l15 = lane & 15, l4 = lane >> 4;
  const int qbase = qi * 64 + w * 16;
  const int LDQ = 2048;

  // Q fragments (B-operand: lane holds Q[q=l15][d=l4*8+j], two d-halves)
  const size_t qrow = (size_t)(b * SEQ + qbase + l15) * LDQ + h * 64;
  bf16x8 Qf0 = *(const bf16x8*)(QKb + qrow + l4 * 8);
  bf16x8 Qf1 = *(const bf16x8*)(QKb + qrow + 32 + l4 * 8);

  const unsigned short* Kbase = QKb + (size_t)b * SEQ * LDQ + 1024 + h * 64;
  const unsigned short* Vbase = Vt + (size_t)(h * 64) * MROWS + (size_t)b * SEQ;

  f32x4 O[4] = {};
  float mrun = -1e30f, lrun = 0.f;
  const int nt = qi + 1;                          // same tile count for all 4 waves
  const float c1s = 0.1803368801111204f;          // (1/sqrt(64)) * log2(e)

  const int srow = tid >> 3, spos = tid & 7;      // staging: chunk c=tid+i*256

  for (int t = 0; t < nt; ++t) {
    const int kv0 = t * 64;
    // stage K tile [kv=64][d=64] and V^T tile [v=64][kv=64]
    // (swizzled source col-block = spos^(row&7)  ->  linear LDS write)
#pragma unroll
    for (int i = 0; i < 2; ++i) {
      const int row = srow + i * 32;
      const int sc = (spos ^ (row & 7)) * 8;
      gload_lds16(Kbase + (size_t)(kv0 + row) * LDQ + sc,
                  (void*)(Ks + (tid + i * 256) * 8));
      gload_lds16(Vbase + (size_t)row * MROWS + kv0 + sc,
                  (void*)(Vs + (tid + i * 256) * 8));
    }
    __syncthreads();

    const bool last = (t == nt - 1);

    // ---- QK^T: T[kt] covers kv = kt*16 + l4*4 + r (row), q = l15 (col) ----
    f32x4 T[4];
#pragma unroll
    for (int kt = 0; kt < 4; ++kt) {
      const int r = kt * 16 + l15;
      const unsigned short* Kb = Ks + r * 64;
      bf16x8 k0 = *(const bf16x8*)(Kb + ((l4 ^ (r & 7)) * 8));
      bf16x8 k1 = *(const bf16x8*)(Kb + (((4 + l4) ^ (r & 7)) * 8));
      f32x4 a = {};
      a = __builtin_amdgcn_mfma_f32_16x16x32_bf16(k0, Qf0, a, 0, 0, 0);
      a = __builtin_amdgcn_mfma_f32_16x16x32_bf16(k1, Qf1, a, 0, 0, 0);
      T[kt] = a;
    }
    if (last) {   // universal causal mask: kv_local > q_local (covers partial + full)
      const int ql = w * 16 + l15;
#pragma unroll
      for (int kt = 0; kt < 4; ++kt)
#pragma unroll
        for (int r2 = 0; r2 < 4; ++r2)
          if (kt * 16 + l4 * 4 + r2 > ql) T[kt][r2] = -1e30f;
    }

    // ---- online softmax (stats per q=l15, replicated across l4 groups) ----
    float mx = -1e30f;
#pragma unroll
    for (int kt = 0; kt < 4; ++kt)
      mx = fmaxf(mx, fmaxf(fmaxf(T[kt][0], T[kt][1]), fmaxf(T[kt][2], T[kt][3])));
    mx = fmaxf(mx, __shfl_xor(mx, 16));
    mx = fmaxf(mx, __shfl_xor(mx, 32));
    const float mnew = fmaxf(mrun, mx * c1s);
    float p[16];
    float rs = 0.f;
#pragma unroll
    for (int kt = 0; kt < 4; ++kt)
#pragma unroll
      for (int r = 0; r < 4; ++r) {
        float pv = exp2f(T[kt][r] * c1s - mnew);
        p[kt * 4 + r] = pv;
        rs += pv;
      }
    rs += __shfl_xor(rs, 16);
    rs += __shfl_xor(rs, 32);
    const float alpha = exp2f(mrun - mnew);
    lrun = lrun * alpha + rs;
    mrun = mnew;

    // ---- rescale O (O rows are q=l4*4+j -> fetch alpha from stat lane) ----
    const float a0 = __shfl(alpha, l4 * 4 + 0);
    const float a1 = __shfl(alpha, l4 * 4 + 1);
    const float a2 = __shfl(alpha, l4 * 4 + 2);
    const float a3 = __shfl(alpha, l4 * 4 + 3);
#pragma unroll
    for (int vb = 0; vb < 4; ++vb) {
      O[vb][0] *= a0; O[vb][1] *= a1; O[vb][2] *= a2; O[vb][3] *= a3;
    }

    // ---- PV: O[q][v] += P[q][kv] * V[kv][v], A=P^T-regs, B=V^T tile ----
#pragma unroll
    for (int kt = 0; kt < 4; ++kt) {
      bf16x4 pb;
#pragma unroll
      for (int r = 0; r < 4; ++r) pb[r] = (short)f2bf(p[kt * 4 + r]);
#pragma unroll
      for (int vb = 0; vb < 4; ++vb) {
        const int vr = vb * 16 + l15;
        const int c0 = kt * 16 + l4 * 4;
        const int sw = ((((c0 >> 3) ^ (vr & 7)) << 3) | (c0 & 7));
        bf16x4 vf = *(const bf16x4*)(Vs + vr * 64 + sw);
        O[vb] = __builtin_amdgcn_mfma_f32_16x16x16bf16_1k(pb, vf, O[vb], 0, 0, 0);
      }
    }
    __syncthreads();   // all waves done reading Ks/Vs before next stage
  }

  const float linv = 1.f / lrun;
  const float i0 = __shfl(linv, l4 * 4 + 0);
  const float i1 = __shfl(linv, l4 * 4 + 1);
  const float i2 = __shfl(linv, l4 * 4 + 2);
  const float i3 = __shfl(linv, l4 * 4 + 3);
#pragma unroll
  for (int vb = 0; vb < 4; ++vb) {
    const size_t base = (size_t)(b * SEQ + qbase) * 1024 + h * 64 + vb * 16 + l15;
    Oout[base + (size_t)(l4 * 4 + 0) * 1024] = f2bf(O[vb][0] * i0);
    Oout[base + (size_t)(l4 * 4 + 1) * 1024] = f2bf(O[vb][1] * i1);
    Oout[base + (size_t)(l4 * 4 + 2) * 1024] = f2bf(O[vb][2] * i2);
    Oout[base + (size_t)(l4 * 4 + 3) * 1024] = f2bf(O[vb][3] * i3);
  }
}

// ---------- launcher ----------
extern "C" void kernel_launch(void* const* d_in, const int* in_sizes, int n_in,
                              void* d_out, int out_size, void* d_ws, size_t ws_size,
                              hipStream_t stream) {
  const float* x  = (const float*)d_in[0];
  const float* WQ = (const float*)d_in[1];
  const float* WK = (const float*)d_in[2];
  const float* WV = (const float*)d_in[3];
  const float* WO = (const float*)d_in[4];
  float* out = (float*)d_out;

  char* ws = (char*)d_ws;
  // ws layout (bytes), total 75.5 MB:
  //   QKb : 8192*2048*2 = 33554432
  //   Vtb : 1024*8192*2 = 16777216
  //   xb  : 8192*1024*2 = 16777216   (reused as attn output)
  //   Wqk : 2048*1024*2 =  4194304
  //   WVb : 1024*1024*2 =  2097152
  //   WOt : 1024*1024*2 =  2097152
  unsigned short* QKb = (unsigned short*)ws;
  unsigned short* Vtb = (unsigned short*)(ws + 33554432);
  unsigned short* xb  = (unsigned short*)(ws + 50331648);
  unsigned short* Wqk = (unsigned short*)(ws + 67108864);
  unsigned short* WVb = (unsigned short*)(ws + 71303168);
  unsigned short* WOt = (unsigned short*)(ws + 73400320);
  unsigned short* attnb = xb;   // xb consumed by both GEMMs before attn writes it

  // converts
  cvt_f32_bf16<<<8192, 256, 0, stream>>>(x, xb, 2097152);
  cvt_f32_bf16<<<1024, 256, 0, stream>>>(WQ, Wqk, 262144);
  cvt_f32_bf16<<<1024, 256, 0, stream>>>(WK, Wqk + 1048576, 262144);
  cvt_f32_bf16<<<1024, 256, 0, stream>>>(WV, WVb, 262144);
  wot_kernel<<<4096, 256, 0, stream>>>(WO, WOt);

  // QK projection: [8192,1024] x [2048,1024]^T -> QKb [8192,2048] bf16
  gemm_bt<true><<<(MROWS / 128) * (2048 / 128), 256, 0, stream>>>(
      xb, Wqk, QKb, MROWS, 2048, DMODEL, 2048);

  // V^T projection: WV [1024(hv),1024(d)] x xb[8192,1024]^T -> Vtb [1024(hv),8192(s)] bf16
  gemm_bt<true><<<(1024 / 128) * (MROWS / 128), 256, 0, stream>>>(
      WVb, xb, Vtb, 1024, MROWS, DMODEL, MROWS);

  // causal flash attention -> attnb [8192,1024] bf16
  attn_fwd<<<(SEQ / 64) * 64, 256, 0, stream>>>(QKb, Vtb, attnb);

  // output projection: [8192,1024] x [1024,1024]^T -> out [8192,1024] fp32
  gemm_bt<false><<<(MROWS / 128) * (DMODEL / 128), 256, 0, stream>>>(
      attnb, WOt, out, MROWS, DMODEL, DMODEL, DMODEL);
}

// Round 5
// 199.476 us; speedup vs baseline: 1.1346x; 1.0568x over previous
//
#include <hip/hip_runtime.h>
#include <hip/hip_bf16.h>
#include <stdint.h>
#include <stddef.h>

// ---------- types ----------
typedef __attribute__((ext_vector_type(8))) short bf16x8;   // 8 bf16 (4 VGPR)
typedef __attribute__((ext_vector_type(4))) short bf16x4;   // 4 bf16 (2 VGPR)
typedef __attribute__((ext_vector_type(4))) float f32x4;
typedef __attribute__((ext_vector_type(4))) unsigned short u16x4;

#define DEVI static __device__ __forceinline__

// problem constants
static constexpr int BATCH = 4;
static constexpr int SEQ   = 2048;
static constexpr int DMODEL = 1024;
static constexpr int MROWS = BATCH * SEQ;          // 8192

DEVI unsigned short f2bf(float f) {
  union { float f; unsigned int u; } c; c.f = f;
  unsigned int u = c.u;
  unsigned int r = u + 0x7fffu + ((u >> 16) & 1u);   // RNE
  return (unsigned short)(r >> 16);
}

DEVI void gload_lds16(const void* g, void* l) {
  __builtin_amdgcn_global_load_lds(
      (const __attribute__((address_space(1))) void*)g,
      (__attribute__((address_space(3))) void*)l, 16, 0, 0);
}

// ---------- fp32 -> bf16 convert (vectorized, n multiple of 4) ----------
__global__ void cvt_f32_bf16(const float* __restrict__ src,
                             unsigned short* __restrict__ dst, int n4) {
  int i = blockIdx.x * blockDim.x + threadIdx.x;
  if (i >= n4) return;
  f32x4 v = *(const f32x4*)(src + (size_t)i * 4);
  u16x4 o;
  o[0] = f2bf(v[0]); o[1] = f2bf(v[1]); o[2] = f2bf(v[2]); o[3] = f2bf(v[3]);
  *(u16x4*)(dst + (size_t)i * 4) = o;
}

// ---------- WO[h][d][v] (fp32) -> WOt[d][h*64+v] (bf16) ----------
__global__ void wot_kernel(const float* __restrict__ WO,
                           unsigned short* __restrict__ WOt) {
  int i = blockIdx.x * 256 + threadIdx.x;      // 1M threads
  int d = i >> 10, k = i & 1023;
  int h = k >> 6, v = k & 63;
  WOt[i] = f2bf(WO[(size_t)(h * 1024 + d) * 64 + v]);
}

// ---------- bf16 GEMM: C[M,N] = A[M,K] * Bt[N,K]^T ----------
// 128x128 tile, BK=64, 4 waves, global_load_lds w/ pre-swizzled source,
// XOR-swizzled LDS reads.  [round-1 verified]
// + T1: XCD-bijective blockIdx swizzle (requires gridDim.x % 8 == 0).
template <bool OUTBF>
__global__ __launch_bounds__(256)
void gemm_bt(const unsigned short* __restrict__ A,
             const unsigned short* __restrict__ Bt,
             void* __restrict__ Cv, int M, int N, int K, int ldc) {
  __shared__ unsigned short As[128 * 64];
  __shared__ unsigned short Bs[128 * 64];
  const int tid = threadIdx.x;
  const int lane = tid & 63;
  const int w = tid >> 6;
  const int wr = w >> 1, wc = w & 1;
  const int l15 = lane & 15, l4 = lane >> 4;
  const int nbn = N >> 7;
  // XCD swizzle: blocks with bid%8==x (dispatched to XCD x) get a contiguous
  // chunk of tile space -> shared A/B panels within an XCD's private L2.
  const int nwg = gridDim.x;
  const int bid = (blockIdx.x & 7) * (nwg >> 3) + (blockIdx.x >> 3);
  const int mblk = bid / nbn, nblk = bid % nbn;
  const unsigned short* Ab = A + (size_t)mblk * 128 * K;
  const unsigned short* Bb = Bt + (size_t)nblk * 128 * K;
  f32x4 acc[4][4] = {};

  const int srow = tid >> 3;     // staging: chunk c = tid + i*256 -> row=c>>3, pos=c&7
  const int spos = tid & 7;

  for (int k0 = 0; k0 < K; k0 += 64) {
#pragma unroll
    for (int i = 0; i < 4; ++i) {
      int row = srow + i * 32;
      int sc = spos ^ (row & 7);   // pre-swizzled source so linear LDS write = swizzled layout
      gload_lds16(Ab + (size_t)row * K + k0 + sc * 8, (void*)(As + (tid + i * 256) * 8));
      gload_lds16(Bb + (size_t)row * K + k0 + sc * 8, (void*)(Bs + (tid + i * 256) * 8));
    }
    __syncthreads();
    bf16x8 af[2][4], bq[2][4];
#pragma unroll
    for (int cc = 0; cc < 2; ++cc) {
#pragma unroll
      for (int m = 0; m < 4; ++m) {
        int ra = wr * 64 + m * 16 + l15;
        af[cc][m] = *(const bf16x8*)(As + ra * 64 + (((cc * 4 + l4) ^ (ra & 7)) * 8));
        int rb = wc * 64 + m * 16 + l15;
        bq[cc][m] = *(const bf16x8*)(Bs + rb * 64 + (((cc * 4 + l4) ^ (rb & 7)) * 8));
      }
    }
#pragma unroll
    for (int cc = 0; cc < 2; ++cc)
#pragma unroll
      for (int m = 0; m < 4; ++m)
#pragma unroll
        for (int n = 0; n < 4; ++n)
          acc[m][n] = __builtin_amdgcn_mfma_f32_16x16x32_bf16(af[cc][m], bq[cc][n], acc[m][n], 0, 0, 0);
    __syncthreads();
  }

#pragma unroll
  for (int m = 0; m < 4; ++m)
#pragma unroll
    for (int n = 0; n < 4; ++n) {
      int col = nblk * 128 + wc * 64 + n * 16 + l15;
#pragma unroll
      for (int j = 0; j < 4; ++j) {
        int row = mblk * 128 + wr * 64 + m * 16 + l4 * 4 + j;   // D: col=l&15, row=(l>>4)*4+j
        if (OUTBF)
          ((unsigned short*)Cv)[(size_t)row * ldc + col] = f2bf(acc[m][n][j]);
        else
          ((float*)Cv)[(size_t)row * ldc + col] = acc[m][n][j];
      }
    }
}

// ---------- flash attention (causal), v5 ----------
// v3 (verified) + defer-rescale ONLY (T13, log2-domain THR=10 => P <= 2^10,
// f32 accumulators have ample headroom; numerator/denominator share stale-m scale).
// Library exp2f and f2bf packing kept exactly as the verified v3.
__global__ __launch_bounds__(256)
void attn_fwd(const unsigned short* __restrict__ QKb,
              const unsigned short* __restrict__ Vt,
              unsigned short* __restrict__ Oout) {
  __shared__ unsigned short Ks[64 * 64];
  __shared__ unsigned short Vs[64 * 64];
  const int bid = blockIdx.x;
  const int qi = 31 - (bid >> 6);          // reversed: heavy blocks dispatch first
  const int bh = bid & 63;
  const int b = bh >> 4, h = bh & 15;
  const int tid = threadIdx.x, lane = tid & 63, w = tid >> 6;
  const int l15 = lane & 15, l4 = lane >> 4;
  const int qbase = qi * 64 + w * 16;
  const int LDQ = 2048;

  // Q fragments (B-operand: lane holds Q[q=l15][d=l4*8+j], two d-halves)
  const size_t qrow = (size_t)(b * SEQ + qbase + l15) * LDQ + h * 64;
  bf16x8 Qf0 = *(const bf16x8*)(QKb + qrow + l4 * 8);
  bf16x8 Qf1 = *(const bf16x8*)(QKb + qrow + 32 + l4 * 8);

  const unsigned short* Kbase = QKb + (size_t)b * SEQ * LDQ + 1024 + h * 64;
  const unsigned short* Vbase = Vt + (size_t)(h * 64) * MROWS + (size_t)b * SEQ;

  f32x4 O[4] = {};
  float mrun = -1e30f, lrun = 0.f;
  const int nt = qi + 1;                          // same tile count for all 4 waves
  const float c1s = 0.1803368801111204f;          // (1/sqrt(64)) * log2(e)

  const int srow = tid >> 3, spos = tid & 7;      // staging: chunk c=tid+i*256

  for (int t = 0; t < nt; ++t) {
    const int kv0 = t * 64;
    // stage K tile [kv=64][d=64] and V^T tile [v=64][kv=64]
#pragma unroll
    for (int i = 0; i < 2; ++i) {
      const int row = srow + i * 32;
      const int sc = (spos ^ (row & 7)) * 8;
      gload_lds16(Kbase + (size_t)(kv0 + row) * LDQ + sc,
                  (void*)(Ks + (tid + i * 256) * 8));
      gload_lds16(Vbase + (size_t)row * MROWS + kv0 + sc,
                  (void*)(Vs + (tid + i * 256) * 8));
    }
    __syncthreads();

    const bool last = (t == nt - 1);

    // ---- QK^T: T[kt] covers kv = kt*16 + l4*4 + r (row), q = l15 (col) ----
    f32x4 T[4];
#pragma unroll
    for (int kt = 0; kt < 4; ++kt) {
      const int r = kt * 16 + l15;
      const unsigned short* Kb = Ks + r * 64;
      bf16x8 k0 = *(const bf16x8*)(Kb + ((l4 ^ (r & 7)) * 8));
      bf16x8 k1 = *(const bf16x8*)(Kb + (((4 + l4) ^ (r & 7)) * 8));
      f32x4 a = {};
      a = __builtin_amdgcn_mfma_f32_16x16x32_bf16(k0, Qf0, a, 0, 0, 0);
      a = __builtin_amdgcn_mfma_f32_16x16x32_bf16(k1, Qf1, a, 0, 0, 0);
      T[kt] = a;
    }
    if (last) {   // universal causal mask: kv_local > q_local (covers partial + full)
      const int ql = w * 16 + l15;
#pragma unroll
      for (int kt = 0; kt < 4; ++kt)
#pragma unroll
        for (int r2 = 0; r2 < 4; ++r2)
          if (kt * 16 + l4 * 4 + r2 > ql) T[kt][r2] = -1e30f;
    }

    // ---- online softmax (stats per q=l15, replicated across l4 groups) ----
    float mx = -1e30f;
#pragma unroll
    for (int kt = 0; kt < 4; ++kt)
      mx = fmaxf(mx, fmaxf(fmaxf(T[kt][0], T[kt][1]), fmaxf(T[kt][2], T[kt][3])));
    mx = fmaxf(mx, __shfl_xor(mx, 16));
    mx = fmaxf(mx, __shfl_xor(mx, 32));
    const float mx2 = mx * c1s;

    // defer-rescale (T13): keep stale m unless some row's max moved > 10 log2.
    // Numerator (PV, scale 2^-mrun) and denominator (lrun) stay consistent.
    const bool need = __any(mx2 - mrun > 10.0f);
    float mnew = mrun;
    if (need) mnew = fmaxf(mrun, mx2);

    float p[16];
    float rs = 0.f;
#pragma unroll
    for (int kt = 0; kt < 4; ++kt)
#pragma unroll
      for (int r = 0; r < 4; ++r) {
        float pv = exp2f(T[kt][r] * c1s - mnew);
        p[kt * 4 + r] = pv;
        rs += pv;
      }
    rs += __shfl_xor(rs, 16);
    rs += __shfl_xor(rs, 32);

    if (need) {
      const float alpha = exp2f(mrun - mnew);
      lrun = lrun * alpha + rs;
      mrun = mnew;
      // rescale O (O rows are q=l4*4+j -> fetch alpha from stat lane)
      const float a0 = __shfl(alpha, l4 * 4 + 0);
      const float a1 = __shfl(alpha, l4 * 4 + 1);
      const float a2 = __shfl(alpha, l4 * 4 + 2);
      const float a3 = __shfl(alpha, l4 * 4 + 3);
#pragma unroll
      for (int vb = 0; vb < 4; ++vb) {
        O[vb][0] *= a0; O[vb][1] *= a1; O[vb][2] *= a2; O[vb][3] *= a3;
      }
    } else {
      lrun += rs;
    }

    // ---- PV: O[q][v] += P[q][kv] * V[kv][v], A=P^T-regs, B=V^T tile ----
#pragma unroll
    for (int kt = 0; kt < 4; ++kt) {
      bf16x4 pb;
#pragma unroll
      for (int r = 0; r < 4; ++r) pb[r] = (short)f2bf(p[kt * 4 + r]);
#pragma unroll
      for (int vb = 0; vb < 4; ++vb) {
        const int vr = vb * 16 + l15;
        const int c0 = kt * 16 + l4 * 4;
        const int sw = ((((c0 >> 3) ^ (vr & 7)) << 3) | (c0 & 7));
        bf16x4 vf = *(const bf16x4*)(Vs + vr * 64 + sw);
        O[vb] = __builtin_amdgcn_mfma_f32_16x16x16bf16_1k(pb, vf, O[vb], 0, 0, 0);
      }
    }
    __syncthreads();   // all waves done reading Ks/Vs before next stage
  }

  const float linv = 1.f / lrun;
  const float i0 = __shfl(linv, l4 * 4 + 0);
  const float i1 = __shfl(linv, l4 * 4 + 1);
  const float i2 = __shfl(linv, l4 * 4 + 2);
  const float i3 = __shfl(linv, l4 * 4 + 3);
#pragma unroll
  for (int vb = 0; vb < 4; ++vb) {
    const size_t base = (size_t)(b * SEQ + qbase) * 1024 + h * 64 + vb * 16 + l15;
    Oout[base + (size_t)(l4 * 4 + 0) * 1024] = f2bf(O[vb][0] * i0);
    Oout[base + (size_t)(l4 * 4 + 1) * 1024] = f2bf(O[vb][1] * i1);
    Oout[base + (size_t)(l4 * 4 + 2) * 1024] = f2bf(O[vb][2] * i2);
    Oout[base + (size_t)(l4 * 4 + 3) * 1024] = f2bf(O[vb][3] * i3);
  }
}

// ---------- launcher ----------
extern "C" void kernel_launch(void* const* d_in, const int* in_sizes, int n_in,
                              void* d_out, int out_size, void* d_ws, size_t ws_size,
                              hipStream_t stream) {
  const float* x  = (const float*)d_in[0];
  const float* WQ = (const float*)d_in[1];
  const float* WK = (const float*)d_in[2];
  const float* WV = (const float*)d_in[3];
  const float* WO = (const float*)d_in[4];
  float* out = (float*)d_out;

  char* ws = (char*)d_ws;
  // ws layout (bytes), total 75.5 MB:
  //   QKb : 8192*2048*2 = 33554432
  //   Vtb : 1024*8192*2 = 16777216
  //   xb  : 8192*1024*2 = 16777216   (reused as attn output)
  //   Wqk : 2048*1024*2 =  4194304
  //   WVb : 1024*1024*2 =  2097152
  //   WOt : 1024*1024*2 =  2097152
  unsigned short* QKb = (unsigned short*)ws;
  unsigned short* Vtb = (unsigned short*)(ws + 33554432);
  unsigned short* xb  = (unsigned short*)(ws + 50331648);
  unsigned short* Wqk = (unsigned short*)(ws + 67108864);
  unsigned short* WVb = (unsigned short*)(ws + 71303168);
  unsigned short* WOt = (unsigned short*)(ws + 73400320);
  unsigned short* attnb = xb;   // xb consumed by both GEMMs before attn writes it

  // converts
  cvt_f32_bf16<<<8192, 256, 0, stream>>>(x, xb, 2097152);
  cvt_f32_bf16<<<1024, 256, 0, stream>>>(WQ, Wqk, 262144);
  cvt_f32_bf16<<<1024, 256, 0, stream>>>(WK, Wqk + 1048576, 262144);
  cvt_f32_bf16<<<1024, 256, 0, stream>>>(WV, WVb, 262144);
  wot_kernel<<<4096, 256, 0, stream>>>(WO, WOt);

  // QK projection: [8192,1024] x [2048,1024]^T -> QKb [8192,2048] bf16
  gemm_bt<true><<<(MROWS / 128) * (2048 / 128), 256, 0, stream>>>(
      xb, Wqk, QKb, MROWS, 2048, DMODEL, 2048);

  // V^T projection: WV [1024(hv),1024(d)] x xb[8192,1024]^T -> Vtb [1024(hv),8192(s)] bf16
  gemm_bt<true><<<(1024 / 128) * (MROWS / 128), 256, 0, stream>>>(
      WVb, xb, Vtb, 1024, MROWS, DMODEL, MROWS);

  // causal flash attention -> attnb [8192,1024] bf16
  attn_fwd<<<(SEQ / 64) * 64, 256, 0, stream>>>(QKb, Vtb, attnb);

  // output projection: [8192,1024] x [1024,1024]^T -> out [8192,1024] fp32
  gemm_bt<false><<<(MROWS / 128) * (DMODEL / 128), 256, 0, stream>>>(
      attnb, WOt, out, MROWS, DMODEL, DMODEL, DMODEL);
}

// Round 6
// 189.326 us; speedup vs baseline: 1.1954x; 1.0536x over previous
//
#include <hip/hip_runtime.h>
#include <hip/hip_bf16.h>
#include <stdint.h>
#include <stddef.h>

// ---------- types ----------
typedef __attribute__((ext_vector_type(8))) short bf16x8;   // 8 bf16 (4 VGPR)
typedef __attribute__((ext_vector_type(4))) short bf16x4;   // 4 bf16 (2 VGPR)
typedef __attribute__((ext_vector_type(4))) float f32x4;
typedef __attribute__((ext_vector_type(4))) unsigned short u16x4;

#define DEVI static __device__ __forceinline__

// problem constants
static constexpr int BATCH = 4;
static constexpr int SEQ   = 2048;
static constexpr int DMODEL = 1024;
static constexpr int MROWS = BATCH * SEQ;          // 8192

DEVI unsigned short f2bf(float f) {
  union { float f; unsigned int u; } c; c.f = f;
  unsigned int u = c.u;
  unsigned int r = u + 0x7fffu + ((u >> 16) & 1u);   // RNE
  return (unsigned short)(r >> 16);
}

DEVI unsigned short f2bf_trunc(float f) {      // for non-negative P only
  union { float f; unsigned int u; } c; c.f = f;
  return (unsigned short)(c.u >> 16);
}

DEVI void gload_lds16(const void* g, void* l) {
  __builtin_amdgcn_global_load_lds(
      (const __attribute__((address_space(1))) void*)g,
      (__attribute__((address_space(3))) void*)l, 16, 0, 0);
}

// ---------- fp32 -> bf16 convert (vectorized, n multiple of 4) ----------
__global__ void cvt_f32_bf16(const float* __restrict__ src,
                             unsigned short* __restrict__ dst, int n4) {
  int i = blockIdx.x * blockDim.x + threadIdx.x;
  if (i >= n4) return;
  f32x4 v = *(const f32x4*)(src + (size_t)i * 4);
  u16x4 o;
  o[0] = f2bf(v[0]); o[1] = f2bf(v[1]); o[2] = f2bf(v[2]); o[3] = f2bf(v[3]);
  *(u16x4*)(dst + (size_t)i * 4) = o;
}

// ---------- WO[h][d][v] (fp32) -> WOt[d][h*64+v] (bf16) ----------
__global__ void wot_kernel(const float* __restrict__ WO,
                           unsigned short* __restrict__ WOt) {
  int i = blockIdx.x * 256 + threadIdx.x;      // 1M threads
  int d = i >> 10, k = i & 1023;
  int h = k >> 6, v = k & 63;
  WOt[i] = f2bf(WO[(size_t)(h * 1024 + d) * 64 + v]);
}

// ---------- bf16 GEMM: C[M,N] = A[M,K] * Bt[N,K]^T ----------
// 128x128 tile, BK=64, 4 waves, global_load_lds w/ pre-swizzled source,
// XOR-swizzled LDS reads.  [round-1 verified]
// + T1 XCD-bijective blockIdx swizzle (requires gridDim.x % 8 == 0).
// + epilogue scale: cols < scale_cols get *cscale (pre-scales Q by c1s).
template <bool OUTBF>
__global__ __launch_bounds__(256)
void gemm_bt(const unsigned short* __restrict__ A,
             const unsigned short* __restrict__ Bt,
             void* __restrict__ Cv, int M, int N, int K, int ldc,
             float cscale, int scale_cols) {
  __shared__ unsigned short As[128 * 64];
  __shared__ unsigned short Bs[128 * 64];
  const int tid = threadIdx.x;
  const int lane = tid & 63;
  const int w = tid >> 6;
  const int wr = w >> 1, wc = w & 1;
  const int l15 = lane & 15, l4 = lane >> 4;
  const int nbn = N >> 7;
  const int nwg = gridDim.x;
  const int bid = (blockIdx.x & 7) * (nwg >> 3) + (blockIdx.x >> 3);
  const int mblk = bid / nbn, nblk = bid % nbn;
  const unsigned short* Ab = A + (size_t)mblk * 128 * K;
  const unsigned short* Bb = Bt + (size_t)nblk * 128 * K;
  f32x4 acc[4][4] = {};

  const int srow = tid >> 3;     // staging: chunk c = tid + i*256 -> row=c>>3, pos=c&7
  const int spos = tid & 7;

  for (int k0 = 0; k0 < K; k0 += 64) {
#pragma unroll
    for (int i = 0; i < 4; ++i) {
      int row = srow + i * 32;
      int sc = spos ^ (row & 7);   // pre-swizzled source so linear LDS write = swizzled layout
      gload_lds16(Ab + (size_t)row * K + k0 + sc * 8, (void*)(As + (tid + i * 256) * 8));
      gload_lds16(Bb + (size_t)row * K + k0 + sc * 8, (void*)(Bs + (tid + i * 256) * 8));
    }
    __syncthreads();
    bf16x8 af[2][4], bq[2][4];
#pragma unroll
    for (int cc = 0; cc < 2; ++cc) {
#pragma unroll
      for (int m = 0; m < 4; ++m) {
        int ra = wr * 64 + m * 16 + l15;
        af[cc][m] = *(const bf16x8*)(As + ra * 64 + (((cc * 4 + l4) ^ (ra & 7)) * 8));
        int rb = wc * 64 + m * 16 + l15;
        bq[cc][m] = *(const bf16x8*)(Bs + rb * 64 + (((cc * 4 + l4) ^ (rb & 7)) * 8));
      }
    }
#pragma unroll
    for (int cc = 0; cc < 2; ++cc)
#pragma unroll
      for (int m = 0; m < 4; ++m)
#pragma unroll
        for (int n = 0; n < 4; ++n)
          acc[m][n] = __builtin_amdgcn_mfma_f32_16x16x32_bf16(af[cc][m], bq[cc][n], acc[m][n], 0, 0, 0);
    __syncthreads();
  }

#pragma unroll
  for (int m = 0; m < 4; ++m)
#pragma unroll
    for (int n = 0; n < 4; ++n) {
      int col = nblk * 128 + wc * 64 + n * 16 + l15;
      const float s = (col < scale_cols) ? cscale : 1.f;
#pragma unroll
      for (int j = 0; j < 4; ++j) {
        int row = mblk * 128 + wr * 64 + m * 16 + l4 * 4 + j;   // D: col=l&15, row=(l>>4)*4+j
        if (OUTBF)
          ((unsigned short*)Cv)[(size_t)row * ldc + col] = f2bf(acc[m][n][j] * s);
        else
          ((float*)Cv)[(size_t)row * ldc + col] = acc[m][n][j] * s;
      }
    }
}

// ---------- flash attention (causal), v6 ----------
// v5 (verified) + VALU cuts: Q pre-scaled by c1s in GEMM (exp arg = T - m),
// raw v_exp_f32 via __builtin_amdgcn_exp2f, truncating P->bf16 (P >= 0).
__global__ __launch_bounds__(256)
void attn_fwd(const unsigned short* __restrict__ QKb,
              const unsigned short* __restrict__ Vt,
              unsigned short* __restrict__ Oout) {
  __shared__ unsigned short Ks[64 * 64];
  __shared__ unsigned short Vs[64 * 64];
  const int bid = blockIdx.x;
  const int qi = 31 - (bid >> 6);          // reversed: heavy blocks dispatch first
  const int bh = bid & 63;
  const int b = bh >> 4, h = bh & 15;
  const int tid = threadIdx.x, lane = tid & 63, w = tid >> 6;
  const int l15 = lane & 15, l4 = lane >> 4;
  const int qbase = qi * 64 + w * 16;
  const int LDQ = 2048;

  // Q fragments (B-operand: lane holds Q[q=l15][d=l4*8+j], two d-halves)
  // Q is pre-scaled by (1/sqrt(64))*log2(e) in the QK GEMM epilogue.
  const size_t qrow = (size_t)(b * SEQ + qbase + l15) * LDQ + h * 64;
  bf16x8 Qf0 = *(const bf16x8*)(QKb + qrow + l4 * 8);
  bf16x8 Qf1 = *(const bf16x8*)(QKb + qrow + 32 + l4 * 8);

  const unsigned short* Kbase = QKb + (size_t)b * SEQ * LDQ + 1024 + h * 64;
  const unsigned short* Vbase = Vt + (size_t)(h * 64) * MROWS + (size_t)b * SEQ;

  f32x4 O[4] = {};
  float mrun = -1e30f, lrun = 0.f;
  const int nt = qi + 1;                          // same tile count for all 4 waves

  const int srow = tid >> 3, spos = tid & 7;      // staging: chunk c=tid+i*256

  for (int t = 0; t < nt; ++t) {
    const int kv0 = t * 64;
    // stage K tile [kv=64][d=64] and V^T tile [v=64][kv=64]
#pragma unroll
    for (int i = 0; i < 2; ++i) {
      const int row = srow + i * 32;
      const int sc = (spos ^ (row & 7)) * 8;
      gload_lds16(Kbase + (size_t)(kv0 + row) * LDQ + sc,
                  (void*)(Ks + (tid + i * 256) * 8));
      gload_lds16(Vbase + (size_t)row * MROWS + kv0 + sc,
                  (void*)(Vs + (tid + i * 256) * 8));
    }
    __syncthreads();

    const bool last = (t == nt - 1);

    // ---- QK^T: T[kt] covers kv = kt*16 + l4*4 + r (row), q = l15 (col) ----
    // T is already in log2 domain (Q pre-scaled).
    f32x4 T[4];
#pragma unroll
    for (int kt = 0; kt < 4; ++kt) {
      const int r = kt * 16 + l15;
      const unsigned short* Kb = Ks + r * 64;
      bf16x8 k0 = *(const bf16x8*)(Kb + ((l4 ^ (r & 7)) * 8));
      bf16x8 k1 = *(const bf16x8*)(Kb + (((4 + l4) ^ (r & 7)) * 8));
      f32x4 a = {};
      a = __builtin_amdgcn_mfma_f32_16x16x32_bf16(k0, Qf0, a, 0, 0, 0);
      a = __builtin_amdgcn_mfma_f32_16x16x32_bf16(k1, Qf1, a, 0, 0, 0);
      T[kt] = a;
    }
    if (last) {   // universal causal mask: kv_local > q_local (covers partial + full)
      const int ql = w * 16 + l15;
#pragma unroll
      for (int kt = 0; kt < 4; ++kt)
#pragma unroll
        for (int r2 = 0; r2 < 4; ++r2)
          if (kt * 16 + l4 * 4 + r2 > ql) T[kt][r2] = -1e30f;
    }

    // ---- online softmax (stats per q=l15, replicated across l4 groups) ----
    float mx = -1e30f;
#pragma unroll
    for (int kt = 0; kt < 4; ++kt)
      mx = fmaxf(mx, fmaxf(fmaxf(T[kt][0], T[kt][1]), fmaxf(T[kt][2], T[kt][3])));
    mx = fmaxf(mx, __shfl_xor(mx, 16));
    mx = fmaxf(mx, __shfl_xor(mx, 32));

    // defer-rescale (T13): keep stale m unless some row's max moved > 10 log2.
    const bool need = __any(mx - mrun > 10.0f);
    float mnew = mrun;
    if (need) mnew = fmaxf(mrun, mx);

    float p[16];
    float rs = 0.f;
#pragma unroll
    for (int kt = 0; kt < 4; ++kt)
#pragma unroll
      for (int r = 0; r < 4; ++r) {
        float pv = __builtin_amdgcn_exp2f(T[kt][r] - mnew);
        p[kt * 4 + r] = pv;
        rs += pv;
      }
    rs += __shfl_xor(rs, 16);
    rs += __shfl_xor(rs, 32);

    if (need) {
      const float alpha = __builtin_amdgcn_exp2f(mrun - mnew);
      lrun = lrun * alpha + rs;
      mrun = mnew;
      // rescale O (O rows are q=l4*4+j -> fetch alpha from stat lane)
      const float a0 = __shfl(alpha, l4 * 4 + 0);
      const float a1 = __shfl(alpha, l4 * 4 + 1);
      const float a2 = __shfl(alpha, l4 * 4 + 2);
      const float a3 = __shfl(alpha, l4 * 4 + 3);
#pragma unroll
      for (int vb = 0; vb < 4; ++vb) {
        O[vb][0] *= a0; O[vb][1] *= a1; O[vb][2] *= a2; O[vb][3] *= a3;
      }
    } else {
      lrun += rs;
    }

    // ---- PV: O[q][v] += P[q][kv] * V[kv][v], A=P^T-regs, B=V^T tile ----
#pragma unroll
    for (int kt = 0; kt < 4; ++kt) {
      bf16x4 pb;
#pragma unroll
      for (int r = 0; r < 4; ++r) pb[r] = (short)f2bf_trunc(p[kt * 4 + r]);
#pragma unroll
      for (int vb = 0; vb < 4; ++vb) {
        const int vr = vb * 16 + l15;
        const int c0 = kt * 16 + l4 * 4;
        const int sw = ((((c0 >> 3) ^ (vr & 7)) << 3) | (c0 & 7));
        bf16x4 vf = *(const bf16x4*)(Vs + vr * 64 + sw);
        O[vb] = __builtin_amdgcn_mfma_f32_16x16x16bf16_1k(pb, vf, O[vb], 0, 0, 0);
      }
    }
    __syncthreads();   // all waves done reading Ks/Vs before next stage
  }

  const float linv = 1.f / lrun;
  const float i0 = __shfl(linv, l4 * 4 + 0);
  const float i1 = __shfl(linv, l4 * 4 + 1);
  const float i2 = __shfl(linv, l4 * 4 + 2);
  const float i3 = __shfl(linv, l4 * 4 + 3);
#pragma unroll
  for (int vb = 0; vb < 4; ++vb) {
    const size_t base = (size_t)(b * SEQ + qbase) * 1024 + h * 64 + vb * 16 + l15;
    Oout[base + (size_t)(l4 * 4 + 0) * 1024] = f2bf(O[vb][0] * i0);
    Oout[base + (size_t)(l4 * 4 + 1) * 1024] = f2bf(O[vb][1] * i1);
    Oout[base + (size_t)(l4 * 4 + 2) * 1024] = f2bf(O[vb][2] * i2);
    Oout[base + (size_t)(l4 * 4 + 3) * 1024] = f2bf(O[vb][3] * i3);
  }
}

// ---------- launcher ----------
extern "C" void kernel_launch(void* const* d_in, const int* in_sizes, int n_in,
                              void* d_out, int out_size, void* d_ws, size_t ws_size,
                              hipStream_t stream) {
  const float* x  = (const float*)d_in[0];
  const float* WQ = (const float*)d_in[1];
  const float* WK = (const float*)d_in[2];
  const float* WV = (const float*)d_in[3];
  const float* WO = (const float*)d_in[4];
  float* out = (float*)d_out;

  char* ws = (char*)d_ws;
  // ws layout (bytes), total 75.5 MB:
  //   QKb : 8192*2048*2 = 33554432
  //   Vtb : 1024*8192*2 = 16777216
  //   xb  : 8192*1024*2 = 16777216   (reused as attn output)
  //   Wqk : 2048*1024*2 =  4194304
  //   WVb : 1024*1024*2 =  2097152
  //   WOt : 1024*1024*2 =  2097152
  unsigned short* QKb = (unsigned short*)ws;
  unsigned short* Vtb = (unsigned short*)(ws + 33554432);
  unsigned short* xb  = (unsigned short*)(ws + 50331648);
  unsigned short* Wqk = (unsigned short*)(ws + 67108864);
  unsigned short* WVb = (unsigned short*)(ws + 71303168);
  unsigned short* WOt = (unsigned short*)(ws + 73400320);
  unsigned short* attnb = xb;   // xb consumed by both GEMMs before attn writes it

  const float c1s = 0.1803368801111204f;   // (1/sqrt(64)) * log2(e)

  // converts
  cvt_f32_bf16<<<8192, 256, 0, stream>>>(x, xb, 2097152);
  cvt_f32_bf16<<<1024, 256, 0, stream>>>(WQ, Wqk, 262144);
  cvt_f32_bf16<<<1024, 256, 0, stream>>>(WK, Wqk + 1048576, 262144);
  cvt_f32_bf16<<<1024, 256, 0, stream>>>(WV, WVb, 262144);
  wot_kernel<<<4096, 256, 0, stream>>>(WO, WOt);

  // QK projection: [8192,1024] x [2048,1024]^T -> QKb [8192,2048] bf16
  // Q columns (<1024) pre-scaled by c1s.
  gemm_bt<true><<<(MROWS / 128) * (2048 / 128), 256, 0, stream>>>(
      xb, Wqk, QKb, MROWS, 2048, DMODEL, 2048, c1s, 1024);

  // V^T projection: WV [1024(hv),1024(d)] x xb[8192,1024]^T -> Vtb [1024(hv),8192(s)] bf16
  gemm_bt<true><<<(1024 / 128) * (MROWS / 128), 256, 0, stream>>>(
      WVb, xb, Vtb, 1024, MROWS, DMODEL, MROWS, 1.f, 0);

  // causal flash attention -> attnb [8192,1024] bf16
  attn_fwd<<<(SEQ / 64) * 64, 256, 0, stream>>>(QKb, Vtb, attnb);

  // output projection: [8192,1024] x [1024,1024]^T -> out [8192,1024] fp32
  gemm_bt<false><<<(MROWS / 128) * (DMODEL / 128), 256, 0, stream>>>(
      attnb, WOt, out, MROWS, DMODEL, DMODEL, DMODEL, 1.f, 0);
}